// Round 2
// baseline (800.119 us; speedup 1.0000x reference)
//
#include <hip/hip_runtime.h>

// B=8, N=2048, D=F=768. out = softmax((X Wq)(X Wk)^T) (X Wv), fp32 I/O.
// Identity: S = X M X^T with M = Wq Wk^T  -> no K storage; keys = X (fp32 input).
// ws:   G  = fp16(X M)        [16384][768]   at 0          (25,165,824 B)
//       Vt = fp16(X Wv)^T     [8][768][2048] at 25,165,824 (25,165,824 B)
//       total = 50,331,648 B  (== out bytes; fits a ws sized like out)
// d_out scratch (consumed before attn writes out): MT fp32 [768][768] at 0,
//       WvT fp16 [768][768] at byte 2,359,296. attn overwrites all of d_out.

typedef __attribute__((ext_vector_type(8))) _Float16 half8;
typedef __attribute__((ext_vector_type(4))) _Float16 half4v;
typedef __attribute__((ext_vector_type(4))) float floatx4;

__device__ __forceinline__ _Float16 f2h(float f) { return (_Float16)f; }

// ---------------- MT[e][d] = M[d][e], M = Wq Wk^T (fp32 out) ----------------
// A = Wq rows (m=d, k=f contig), B^T = Wk rows (n=e, k=f contig). 128x128 tile.
__global__ __launch_bounds__(256) void mm_small_kernel(const float* __restrict__ Wq,
    const float* __restrict__ Wk, float* __restrict__ MT) {
  __shared__ _Float16 As[128][72];
  __shared__ _Float16 Bs[128][72];
  int bn = blockIdx.x, bm = blockIdx.y;
  int tid = threadIdx.x, lane = tid & 63, wave = tid >> 6;
  int wm = wave >> 1, wn = wave & 1;
  int l15 = lane & 15, quad = lane >> 4;
  floatx4 acc[16];
  for (int i = 0; i < 16; i++) acc[i] = (floatx4){0.f, 0.f, 0.f, 0.f};
  for (int k0 = 0; k0 < 768; k0 += 64) {
    __syncthreads();
    for (int i = 0; i < 8; i++) {
      int f = i * 256 + tid;
      int row = f >> 4, c4 = (f & 15) << 2;
      float4 va = *(const float4*)(Wq + (size_t)(bm * 128 + row) * 768 + k0 + c4);
      *(half4v*)&As[row][c4] = (half4v){f2h(va.x), f2h(va.y), f2h(va.z), f2h(va.w)};
      float4 vb = *(const float4*)(Wk + (size_t)(bn * 128 + row) * 768 + k0 + c4);
      *(half4v*)&Bs[row][c4] = (half4v){f2h(vb.x), f2h(vb.y), f2h(vb.z), f2h(vb.w)};
    }
    __syncthreads();
    for (int kk = 0; kk < 2; kk++) {
      half8 a[4], b[4];
      for (int mt = 0; mt < 4; mt++) a[mt] = *(half8*)&As[wm * 64 + mt * 16 + l15][kk * 32 + quad * 8];
      for (int nt = 0; nt < 4; nt++) b[nt] = *(half8*)&Bs[wn * 64 + nt * 16 + l15][kk * 32 + quad * 8];
      for (int mt = 0; mt < 4; mt++)
        for (int nt = 0; nt < 4; nt++)
          acc[mt * 4 + nt] = __builtin_amdgcn_mfma_f32_16x16x32_f16(a[mt], b[nt], acc[mt * 4 + nt], 0, 0, 0);
    }
  }
  for (int mt = 0; mt < 4; mt++)
    for (int nt = 0; nt < 4; nt++) {
      int e = bn * 128 + wn * 64 + nt * 16 + l15;
      for (int r = 0; r < 4; r++) {
        int d = bm * 128 + wm * 64 + mt * 16 + quad * 4 + r;
        MT[(size_t)e * 768 + d] = acc[mt * 4 + nt][r];   // transposed store
      }
    }
}

// ---------------- WvT[e][d] = Wv[d][e], fp16 ----------------
__global__ void pack_wv_kernel(const float* __restrict__ Wv, _Float16* __restrict__ WvT) {
  __shared__ float tile[32][33];
  int k0 = blockIdx.x * 32;   // d
  int n0 = blockIdx.y * 32;   // e
  int tx = threadIdx.x, ty = threadIdx.y;
  for (int yy = ty; yy < 32; yy += 8)
    tile[yy][tx] = Wv[(size_t)(k0 + yy) * 768 + n0 + tx];
  __syncthreads();
  for (int yy = ty; yy < 32; yy += 8)
    WvT[(size_t)(n0 + yy) * 768 + k0 + tx] = f2h(tile[tx][yy]);
}

// ---------------- G = fp16(X * M): A = X rows, B^T = MT rows ----------------
__global__ __launch_bounds__(256) void proj_g_kernel(const float* __restrict__ X,
    const float* __restrict__ MT, _Float16* __restrict__ G) {
  __shared__ _Float16 As[128][72];
  __shared__ _Float16 Bs[128][72];
  int bn = blockIdx.x, bm = blockIdx.y;
  int tid = threadIdx.x, lane = tid & 63, wave = tid >> 6;
  int wm = wave >> 1, wn = wave & 1;
  int l15 = lane & 15, quad = lane >> 4;
  floatx4 acc[16];
  for (int i = 0; i < 16; i++) acc[i] = (floatx4){0.f, 0.f, 0.f, 0.f};
  for (int k0 = 0; k0 < 768; k0 += 64) {
    __syncthreads();
    for (int i = 0; i < 8; i++) {
      int f = i * 256 + tid;
      int row = f >> 4, c4 = (f & 15) << 2;
      float4 va = *(const float4*)(X + (size_t)(bm * 128 + row) * 768 + k0 + c4);
      *(half4v*)&As[row][c4] = (half4v){f2h(va.x), f2h(va.y), f2h(va.z), f2h(va.w)};
      float4 vb = *(const float4*)(MT + (size_t)(bn * 128 + row) * 768 + k0 + c4);
      *(half4v*)&Bs[row][c4] = (half4v){f2h(vb.x), f2h(vb.y), f2h(vb.z), f2h(vb.w)};
    }
    __syncthreads();
    for (int kk = 0; kk < 2; kk++) {
      half8 a[4], b[4];
      for (int mt = 0; mt < 4; mt++) a[mt] = *(half8*)&As[wm * 64 + mt * 16 + l15][kk * 32 + quad * 8];
      for (int nt = 0; nt < 4; nt++) b[nt] = *(half8*)&Bs[wn * 64 + nt * 16 + l15][kk * 32 + quad * 8];
      for (int mt = 0; mt < 4; mt++)
        for (int nt = 0; nt < 4; nt++)
          acc[mt * 4 + nt] = __builtin_amdgcn_mfma_f32_16x16x32_f16(a[mt], b[nt], acc[mt * 4 + nt], 0, 0, 0);
    }
  }
  for (int mt = 0; mt < 4; mt++)
    for (int nt = 0; nt < 4; nt++) {
      int col = bn * 128 + wn * 64 + nt * 16 + l15;
      for (int r = 0; r < 4; r++) {
        int row = bm * 128 + wm * 64 + mt * 16 + quad * 4 + r;
        G[(size_t)row * 768 + col] = f2h(acc[mt * 4 + nt][r]);
      }
    }
}

// ---------------- Vt[b][d][n] = fp16(X * Wv)^T: A = X rows, B^T = WvT rows ----------------
__global__ __launch_bounds__(256) void proj_v_kernel(const float* __restrict__ X,
    const _Float16* __restrict__ WvT, _Float16* __restrict__ Vt) {
  __shared__ _Float16 As[128][72];
  __shared__ _Float16 Bs[128][72];
  int bn = blockIdx.x, bm = blockIdx.y;
  int tid = threadIdx.x, lane = tid & 63, wave = tid >> 6;
  int wm = wave >> 1, wn = wave & 1;
  int l15 = lane & 15, quad = lane >> 4;
  floatx4 acc[16];
  for (int i = 0; i < 16; i++) acc[i] = (floatx4){0.f, 0.f, 0.f, 0.f};
  for (int k0 = 0; k0 < 768; k0 += 64) {
    __syncthreads();
    for (int i = 0; i < 8; i++) {
      int f = i * 256 + tid;
      int row = f >> 4, c4 = (f & 15) << 2;
      float4 va = *(const float4*)(X + (size_t)(bm * 128 + row) * 768 + k0 + c4);
      *(half4v*)&As[row][c4] = (half4v){f2h(va.x), f2h(va.y), f2h(va.z), f2h(va.w)};
    }
    for (int i = 0; i < 4; i++) {
      int f = i * 256 + tid;
      int row = f >> 3, c8 = (f & 7) << 3;
      *(half8*)&Bs[row][c8] = *(const half8*)(WvT + (size_t)(bn * 128 + row) * 768 + k0 + c8);
    }
    __syncthreads();
    for (int kk = 0; kk < 2; kk++) {
      half8 a[4], b[4];
      for (int mt = 0; mt < 4; mt++) a[mt] = *(half8*)&As[wm * 64 + mt * 16 + l15][kk * 32 + quad * 8];
      for (int nt = 0; nt < 4; nt++) b[nt] = *(half8*)&Bs[wn * 64 + nt * 16 + l15][kk * 32 + quad * 8];
      for (int mt = 0; mt < 4; mt++)
        for (int nt = 0; nt < 4; nt++)
          acc[mt * 4 + nt] = __builtin_amdgcn_mfma_f32_16x16x32_f16(a[mt], b[nt], acc[mt * 4 + nt], 0, 0, 0);
    }
  }
  for (int mt = 0; mt < 4; mt++)
    for (int nt = 0; nt < 4; nt++) {
      int d = bn * 128 + wn * 64 + nt * 16 + l15;             // 0..767
      int tok0 = bm * 128 + wm * 64 + mt * 16 + quad * 4;     // tiles never straddle batches
      int bb = tok0 >> 11, ntok = tok0 & 2047;
      half4v p;
      for (int r = 0; r < 4; r++) p[r] = f2h(acc[mt * 4 + nt][r]);
      *(half4v*)(Vt + (size_t)(bb * 768 + d) * 2048 + ntok) = p;
    }
}

// ---------------- flash attention: 32 q-rows/block, 64-key tiles ----------------
// S-tile: wave w owns keys w*16..+15 (B-frag = fp16(X keys) converted in-reg).
// PV: wave w owns d-slice w*192..+191 (B-frag = Vt rows). G staged in LDS once.
__global__ __launch_bounds__(256) void attn_kernel(const _Float16* __restrict__ G,
    const float* __restrict__ X, const _Float16* __restrict__ Vt, float* __restrict__ out) {
  __shared__ _Float16 Gs[32][776];   // 49,664 B (stride 1552B = 388dw == 4 mod 32: 2-way max)
  __shared__ float Sl[32][68];       // 8,704 B
  __shared__ _Float16 Pl[32][72];    // 4,608 B
  __shared__ float pm[32][8], ps[32][8];
  __shared__ float m_run[32], l_run[32], alpha_s[32];

  int b = blockIdx.y;
  int q0 = blockIdx.x * 32;
  int tid = threadIdx.x;
  int lane = tid & 63, w = tid >> 6;
  int l15 = lane & 15, quad = lane >> 4;
  int row8 = tid >> 3, part = tid & 7;

  if (tid < 32) { m_run[tid] = -1e30f; l_run[tid] = 0.f; }

  floatx4 accO[24];   // [nt][sub]: 12 d-tiles x 2 q-subtiles
  for (int i = 0; i < 24; i++) accO[i] = (floatx4){0.f, 0.f, 0.f, 0.f};

  const _Float16* Gbase = G + (size_t)(b * 2048 + q0) * 768;
  const float*    Xkey  = X + (size_t)b * 2048 * 768;
  const _Float16* Vbase = Vt + (size_t)b * 768 * 2048;

  // stage G block (32x768 fp16) into LDS
  for (int i = 0; i < 12; i++) {
    int f = i * 256 + tid;           // 3072 chunks of 8 halves
    int row = f / 96, c8 = (f % 96) * 8;
    *(half8*)&Gs[row][c8] = *(const half8*)(Gbase + (size_t)row * 768 + c8);
  }
  __syncthreads();

  for (int m0 = 0; m0 < 2048; m0 += 64) {
    // ---- S = G X^T for this block's 32 q-rows vs 64 keys
    floatx4 s0 = (floatx4){0.f, 0.f, 0.f, 0.f}, s1 = (floatx4){0.f, 0.f, 0.f, 0.f};
    const float* Krow = Xkey + (size_t)(m0 + w * 16 + l15) * 768 + quad * 8;
    float4 ka = *(const float4*)Krow;
    float4 kc = *(const float4*)(Krow + 4);
    for (int kb = 0; kb < 24; kb++) {
      int koff = (kb < 23) ? (kb + 1) * 32 : 0;     // depth-1 prefetch (last dummy)
      float4 kan = *(const float4*)(Krow + koff);
      float4 kcn = *(const float4*)(Krow + koff + 4);
      half8 kf = {f2h(ka.x), f2h(ka.y), f2h(ka.z), f2h(ka.w),
                  f2h(kc.x), f2h(kc.y), f2h(kc.z), f2h(kc.w)};
      half8 qa0 = *(half8*)&Gs[l15][kb * 32 + quad * 8];
      half8 qa1 = *(half8*)&Gs[16 + l15][kb * 32 + quad * 8];
      s0 = __builtin_amdgcn_mfma_f32_16x16x32_f16(qa0, kf, s0, 0, 0, 0);
      s1 = __builtin_amdgcn_mfma_f32_16x16x32_f16(qa1, kf, s1, 0, 0, 0);
      ka = kan; kc = kcn;
    }
    {
      int col = w * 16 + l15;
      for (int r = 0; r < 4; r++) Sl[quad * 4 + r][col] = s0[r];
      for (int r = 0; r < 4; r++) Sl[16 + quad * 4 + r][col] = s1[r];
    }
    __syncthreads();
    // ---- online softmax: partial max over the 64 new keys
    {
      float mx = -1e30f;
      for (int j = 0; j < 8; j++) mx = fmaxf(mx, Sl[row8][part * 8 + j]);
      pm[row8][part] = mx;
    }
    __syncthreads();
    if (tid < 32) {
      float mx = pm[tid][0];
      for (int j = 1; j < 8; j++) mx = fmaxf(mx, pm[tid][j]);
      float mold = m_run[tid];
      float mnew = fmaxf(mold, mx);
      m_run[tid] = mnew;
      alpha_s[tid] = __expf(mold - mnew);   // first tile: exp(-1e30)=0
    }
    __syncthreads();
    // ---- P = exp(S - m), partial sums
    {
      float mnew = m_run[row8];
      float sum = 0.f;
      for (int j = 0; j < 8; j++) {
        float p = __expf(Sl[row8][part * 8 + j] - mnew);
        sum += p;
        Pl[row8][part * 8 + j] = f2h(p);
      }
      ps[row8][part] = sum;
    }
    __syncthreads();
    if (tid < 32) {
      float s = 0.f;
      for (int j = 0; j < 8; j++) s += ps[tid][j];
      l_run[tid] = l_run[tid] * alpha_s[tid] + s;
    }
    // ---- O = O*alpha + P V (wave w owns d-slice w*192..+191)
    float al[8];
    for (int ss = 0; ss < 2; ss++)
      for (int r = 0; r < 4; r++) al[ss * 4 + r] = alpha_s[ss * 16 + quad * 4 + r];
    for (int nt = 0; nt < 12; nt++)
      for (int ss = 0; ss < 2; ss++)
        for (int r = 0; r < 4; r++) accO[nt * 2 + ss][r] *= al[ss * 4 + r];
    for (int ks = 0; ks < 2; ks++) {
      half8 pa0 = *(half8*)&Pl[l15][ks * 32 + quad * 8];
      half8 pa1 = *(half8*)&Pl[16 + l15][ks * 32 + quad * 8];
      const _Float16* vb_base = Vbase + (size_t)(w * 192 + l15) * 2048 + m0 + ks * 32 + quad * 8;
      half8 vb = *(const half8*)vb_base;
      for (int nt = 0; nt < 12; nt++) {
        int ntn = (nt < 11) ? nt + 1 : nt;
        half8 vbn = *(const half8*)(vb_base + (size_t)ntn * 16 * 2048);
        accO[nt * 2 + 0] = __builtin_amdgcn_mfma_f32_16x16x32_f16(pa0, vb, accO[nt * 2 + 0], 0, 0, 0);
        accO[nt * 2 + 1] = __builtin_amdgcn_mfma_f32_16x16x32_f16(pa1, vb, accO[nt * 2 + 1], 0, 0, 0);
        vb = vbn;
      }
    }
  }
  __syncthreads();
  if (tid < 32) alpha_s[tid] = 1.f / l_run[tid];
  __syncthreads();
  float il[8];
  for (int ss = 0; ss < 2; ss++)
    for (int r = 0; r < 4; r++) il[ss * 4 + r] = alpha_s[ss * 16 + quad * 4 + r];
  for (int nt = 0; nt < 12; nt++)
    for (int ss = 0; ss < 2; ss++) {
      int d = w * 192 + nt * 16 + l15;
      for (int r = 0; r < 4; r++) {
        int row = q0 + ss * 16 + quad * 4 + r;
        out[(size_t)(b * 2048 + row) * 768 + d] = accO[nt * 2 + ss][r] * il[ss * 4 + r];
      }
    }
}

extern "C" void kernel_launch(void* const* d_in, const int* in_sizes, int n_in,
                              void* d_out, int out_size, void* d_ws, size_t ws_size,
                              hipStream_t stream) {
  (void)in_sizes; (void)n_in; (void)out_size; (void)ws_size;
  const float* X  = (const float*)d_in[0];
  const float* Wq = (const float*)d_in[1];
  const float* Wk = (const float*)d_in[2];
  const float* Wv = (const float*)d_in[3];
  float* out = (float*)d_out;

  char* ws = (char*)d_ws;
  _Float16* G  = (_Float16*)ws;                      // 25,165,824 B
  _Float16* Vt = (_Float16*)(ws + 25165824);         // 25,165,824 B  (total 50,331,648)

  float*    MT  = (float*)d_out;                     // 2,359,296 B  (scratch in out)
  _Float16* WvT = (_Float16*)((char*)d_out + 2359296); // 1,179,648 B (scratch in out)

  mm_small_kernel<<<dim3(6, 6), 256, 0, stream>>>(Wq, Wk, MT);
  pack_wv_kernel<<<dim3(24, 24), dim3(32, 8), 0, stream>>>(Wv, WvT);
  proj_g_kernel<<<dim3(6, 128), 256, 0, stream>>>(X, MT, G);
  proj_v_kernel<<<dim3(6, 128), 256, 0, stream>>>(X, WvT, Vt);
  attn_kernel<<<dim3(64, 8), 256, 0, stream>>>(G, X, Vt, out);
}